// Round 15
// baseline (254.927 us; speedup 1.0000x reference)
//
#include <hip/hip_runtime.h>
#include <hip/hip_bf16.h>
#include <stdint.h>

// eidosNeighborMixer on MI355X:
//   pass 0 (prep_all, fused): W' = rotate(W, theta0+theta1) -> Wt[N][K] bf16;
//            b' = rotate(b) + zero page; xbp = bf16(x) seq-padded.
//   pass 1 : GEMM  out = A @ Wt^T + b'   (A[m,k] = xbp[b][s + k/1024][k%1024])
//            R9 structure (measured best): 256x256 tile, BK=32, 16 waves
//            (4Mx4N, 1024 thr), wave 64x64 (acc 64 VGPR -> 4 waves/SIMD TLP),
//            4-deep LDS ring, global_load_lds staging, XOR chunk swizzle
//            (conflicts 0), counted vmcnt(4), lgkm(0)+setprio MFMA cluster.
//            53% MfmaUtil = ~87% of the 64x64-tile LDS-read roofline.
//            Epilogue writes y as BF16 to ws (halves write traffic; bf16
//            rounding of y adds <=0.011 abs err vs 0.11 threshold).
//   pass 2 : grouped (d%7) RMS norm: reads bf16 y, writes f32 out.

#define SEQ 8192
#define NB 4
#define DM 1024
#define KD 3072

typedef __attribute__((ext_vector_type(8))) short short8_t;
typedef __attribute__((ext_vector_type(4))) float f32x4;

__device__ __forceinline__ unsigned short f2bf(float f) {
  union { float f; uint32_t u; } v; v.f = f;
  return (unsigned short)((v.u + 0x7fffu + ((v.u >> 16) & 1u)) >> 16);  // RNE
}

__device__ __forceinline__ float bf2f(unsigned short u) {
  union { uint32_t u; float f; } v; v.u = (uint32_t)u << 16;
  return v.f;
}

__device__ __forceinline__ void async_ld16(const void* g, void* l) {
  __builtin_amdgcn_global_load_lds(
      (const __attribute__((address_space(1))) uint32_t*)g,
      (__attribute__((address_space(3))) uint32_t*)(uint32_t)(uintptr_t)l,
      16, 0, 0);
}

// -------- prep_all: blocks 0..767 = W rotate+transpose; 768 = bias+zp;
//          769.. = x -> bf16 seq-padded (grid-stride) --------------------
__global__ __launch_bounds__(256) void prep_all(const float* __restrict__ x,
                                                const float* __restrict__ W,
                                                const float* __restrict__ b,
                                                const float* __restrict__ theta,
                                                unsigned short* __restrict__ xbp,
                                                unsigned short* __restrict__ Wt,
                                                float* __restrict__ biasp,
                                                float* __restrict__ zp) {
  const int B0 = blockIdx.x;
  const int t = threadIdx.x;
  if (B0 < 768) {
    __shared__ float csc[32], css[32];
    __shared__ unsigned short tile[64][72];  // [n_local][k_local], padded
    const int bk = B0 % 48, bn = B0 / 48;
    const int k0 = bk * 64, n0 = bn * 64;
    if (t < 32) {
      int d = n0 / 2 + t;
      float ang = theta[d] + theta[512 + d];
      csc[t] = cosf(ang); css[t] = sinf(ang);
    }
    __syncthreads();
#pragma unroll
    for (int i = 0; i < 8; ++i) {
      int idx = i * 256 + t;           // 2048 pairs = 64 k-rows x 32 pairs
      int pr = idx >> 5;               // k row 0..63
      int pc = idx & 31;               // pair col 0..31
      const float2 w2 = *(const float2*)&W[(size_t)(k0 + pr) * DM + n0 + pc * 2];
      float c = csc[pc], s = css[pc];
      tile[pc * 2][pr]     = f2bf(w2.x * c - w2.y * s);
      tile[pc * 2 + 1][pr] = f2bf(w2.x * s + w2.y * c);
    }
    __syncthreads();
#pragma unroll
    for (int i = 0; i < 16; ++i) {
      int idx = i * 256 + t;           // 4096 elems
      int r = idx >> 6, cdx = idx & 63;
      Wt[(size_t)(n0 + r) * KD + k0 + cdx] = tile[r][cdx];
    }
  } else if (B0 == 768) {
#pragma unroll
    for (int p = t; p < 512; p += 256) {
      float ang = theta[p] + theta[512 + p];
      float c = cosf(ang), s = sinf(ang);
      float be = b[2 * p], bo = b[2 * p + 1];
      biasp[2 * p]     = be * c - bo * s;
      biasp[2 * p + 1] = be * s + bo * c;
    }
    ((float4*)zp)[t] = make_float4(0.f, 0.f, 0.f, 0.f);
  } else {
    const size_t total = (size_t)NB * 8194 * 128;  // 16B chunks (8 bf16)
    const size_t nxb = (size_t)(gridDim.x - 769) * 256;
    for (size_t i = (size_t)(B0 - 769) * 256 + t; i < total; i += nxb) {
      int d8 = (int)(i & 127);
      size_t rem = i >> 7;
      int sp = (int)(rem % 8194);
      size_t bb = rem / 8194;
      uint4 o = make_uint4(0u, 0u, 0u, 0u);
      if (sp > 0 && sp < 8193) {
        const float4* src =
            (const float4*)(x + (bb * SEQ + (size_t)(sp - 1)) * DM + d8 * 8);
        float4 lo = src[0], hi = src[1];
        o.x = (uint32_t)f2bf(lo.x) | ((uint32_t)f2bf(lo.y) << 16);
        o.y = (uint32_t)f2bf(lo.z) | ((uint32_t)f2bf(lo.w) << 16);
        o.z = (uint32_t)f2bf(hi.x) | ((uint32_t)f2bf(hi.y) << 16);
        o.w = (uint32_t)f2bf(hi.z) | ((uint32_t)f2bf(hi.w) << 16);
      }
      ((uint4*)xbp)[i] = o;
    }
  }
}

// ---- GEMM: 256x256, BK=32, 16 waves x (64x64), 4-ring, TLP-overlap (R9) ---
// BF16OUT=1: write bf16 y to ws. BF16OUT=0: write f32 (+bias) to out.
template <int BF16OUT>
__global__ __launch_bounds__(1024, 4) void gemm256(const unsigned short* __restrict__ xbp,
                                                   const unsigned short* __restrict__ Wt,
                                                   const float* __restrict__ biasp,
                                                   void* __restrict__ outp) {
  __shared__ __align__(16) unsigned char As[4][16384];  // [buf][256 rows][32 bf16]
  __shared__ __align__(16) unsigned char Bs[4][16384];  // [buf][256 nrow][32 bf16]

  const int tid = threadIdx.x;
  const int lane = tid & 63;
  const int wid = tid >> 6;                   // 0..15
  const int wm = wid >> 2, wn = wid & 3;      // 4M x 4N wave grid
  const int row16 = lane & 15, kgrp = lane >> 4;

  // XCD-bijective swizzle: 512 blocks = 8 XCD x (16 mtiles x 4 ntiles)
  const int L = blockIdx.x;
  const int xcd = L & 7;
  const int j = L >> 3;
  const int mtile = xcd * 16 + (j >> 2);
  const int ntile = j & 3;

  const int n0 = ntile * 256;
  const int batch = mtile >> 5;
  const int s0 = (mtile & 31) * 256;
  const size_t m0 = (size_t)mtile * 256;

  // fragment LDS byte offsets within a 16 KiB buffer (thread-constant)
  int aoff[4], boff[4];
#pragma unroll
  for (int mi = 0; mi < 4; ++mi) {
    int r = wm * 64 + mi * 16 + row16;
    aoff[mi] = r * 64 + (kgrp ^ ((r >> 1) & 3)) * 16;
  }
#pragma unroll
  for (int ni = 0; ni < 4; ++ni) {
    int r = wn * 64 + ni * 16 + row16;
    boff[ni] = r * 64 + (kgrp ^ ((r >> 1) & 3)) * 16;
  }

  // staging: 1024 threads, 1 load each per matrix per K-tile.
  // LDS dest LINEAR; global source chunk pre-swizzled (same XOR as reads).
  const int srow = tid >> 2, sc16 = tid & 3;
  const int scs = sc16 ^ ((srow >> 1) & 3);
  auto stageA = [&](int kt, int buf) {
    const int c = kt >> 5;
    const int ksb = (kt & 31) * 32;
    const size_t base = ((size_t)batch * 8194 + (size_t)(s0 + c)) * DM + ksb;
    async_ld16(xbp + base + (size_t)srow * DM + scs * 8, &As[buf][tid * 16]);
  };
  auto stageB = [&](int kt, int buf) {
    const int kb = kt * 32;
    async_ld16(Wt + (size_t)(n0 + srow) * KD + kb + scs * 8, &Bs[buf][tid * 16]);
  };

  f32x4 acc[4][4];
#pragma unroll
  for (int a = 0; a < 4; ++a)
#pragma unroll
    for (int b = 0; b < 4; ++b) acc[a][b] = (f32x4){0.f, 0.f, 0.f, 0.f};

  // prologue: stage kt 0,1,2 (2 loads each); confirm stage(0); barrier
  stageA(0, 0); stageB(0, 0);
  stageA(1, 1); stageB(1, 1);
  stageA(2, 2); stageB(2, 2);
  asm volatile("s_waitcnt vmcnt(4)" ::: "memory");
  __builtin_amdgcn_s_barrier();

  // per K-tile: stage kt+3, read own 8 frags, lgkm(0) (TLP hides the drain),
  // 16 MFMA under setprio, counted vmcnt, barrier.
  auto body = [&](int kt, int buf, int doStage, int vmN) {
    const int sbuf = (buf + 3) & 3;
    if (doStage) { stageA(kt + 3, sbuf); stageB(kt + 3, sbuf); }
    short8_t af[4], bf[4];
#pragma unroll
    for (int mi = 0; mi < 4; ++mi)
      af[mi] = *(const short8_t*)(&As[buf][0] + aoff[mi]);
#pragma unroll
    for (int ni = 0; ni < 4; ++ni)
      bf[ni] = *(const short8_t*)(&Bs[buf][0] + boff[ni]);
    asm volatile("s_waitcnt lgkmcnt(0)" ::: "memory");
    __builtin_amdgcn_sched_barrier(0);
    __builtin_amdgcn_s_setprio(1);
#pragma unroll
    for (int mi = 0; mi < 4; ++mi)
#pragma unroll
      for (int ni = 0; ni < 4; ++ni)
        acc[mi][ni] = __builtin_amdgcn_mfma_f32_16x16x32_bf16(
            af[mi], bf[ni], acc[mi][ni], 0, 0, 0);
    __builtin_amdgcn_s_setprio(0);
    if (vmN == 4)      asm volatile("s_waitcnt vmcnt(4)" ::: "memory");
    else if (vmN == 2) asm volatile("s_waitcnt vmcnt(2)" ::: "memory");
    else               asm volatile("s_waitcnt vmcnt(0)" ::: "memory");
    __builtin_amdgcn_sched_barrier(0);
    __builtin_amdgcn_s_barrier();
  };

  for (int kt4 = 0; kt4 < 92; kt4 += 4) {
    body(kt4 + 0, 0, 1, 4);
    body(kt4 + 1, 1, 1, 4);
    body(kt4 + 2, 2, 1, 4);
    body(kt4 + 3, 3, 1, 4);
  }
  // tail: kt92 stages kt95; then counted drains per the FIFO ledger
  body(92, 0, 1, 4);
  body(93, 1, 0, 2);
  body(94, 2, 0, 0);
  body(95, 3, 0, 0);

  // epilogue: C[row=kgrp*4+r, col=row16] per 16x16 fragment
#pragma unroll
  for (int mi = 0; mi < 4; ++mi) {
    size_t grow = m0 + (size_t)(wm * 64 + mi * 16 + kgrp * 4);
#pragma unroll
    for (int ni = 0; ni < 4; ++ni) {
      int col = n0 + wn * 64 + ni * 16 + row16;
      float bia = biasp[col];
      if constexpr (BF16OUT) {
        unsigned short* op = (unsigned short*)outp + grow * DM + col;
#pragma unroll
        for (int r = 0; r < 4; ++r) op[(size_t)r * DM] = f2bf(acc[mi][ni][r] + bia);
      } else {
        float* op = (float*)outp + grow * DM + col;
#pragma unroll
        for (int r = 0; r < 4; ++r) op[(size_t)r * DM] = acc[mi][ni][r] + bia;
      }
    }
  }
}

// ---------------- fallback GEMM (fp32 A direct), 128x128 2-barrier ----------
__global__ __launch_bounds__(256) void gemm_fb(const float* __restrict__ Ag,
                                               const unsigned short* __restrict__ Wt,
                                               const float* __restrict__ biasp,
                                               const float* __restrict__ zp,
                                               float* __restrict__ out) {
  __shared__ __align__(16) unsigned char As[128 * 64 * 4];
  __shared__ __align__(16) unsigned char Bs[128 * 64 * 2];

  const int tid = threadIdx.x;
  const int lane = tid & 63;
  const int wid = tid >> 6;
  const int wm = wid >> 1, wn = wid & 1;
  const int row16 = lane & 15, kgrp = lane >> 4;

  const int L = blockIdx.x;
  const int xcd = L & 7;
  const int j = L >> 3;
  const int mtile = xcd * 32 + (j >> 3);
  const int ntile = j & 7;

  const int n0 = ntile * 128;
  const int batch = mtile >> 6;
  const int s0 = (mtile & 63) * 128;
  const size_t m0 = (size_t)mtile * 128;

  f32x4 acc[4][4];
#pragma unroll
  for (int a = 0; a < 4; ++a)
#pragma unroll
    for (int b = 0; b < 4; ++b) acc[a][b] = (f32x4){0.f, 0.f, 0.f, 0.f};

  for (int kt = 0; kt < 48; ++kt) {
    const int c = kt >> 4;
    const int ksb = (kt & 15) * 64;
    __syncthreads();
#pragma unroll
    for (int it = 0; it < 8; ++it) {
      int f16 = it * 256 + tid;
      int row = f16 >> 4, c16 = f16 & 15;
      int c16s = c16 ^ (row & 7);
      int s = s0 + row + c - 1;
      const float* src = (s >= 0 && s < SEQ)
          ? Ag + ((size_t)batch * SEQ + (size_t)s) * DM + ksb + c16s * 4
          : zp + c16s * 4;
      async_ld16(src, As + f16 * 16);
    }
#pragma unroll
    for (int it = 0; it < 4; ++it) {
      int f16 = it * 256 + tid;
      int row = f16 >> 3, c16 = f16 & 7;
      int c16s = c16 ^ (row & 7);
      const unsigned short* src = Wt + (size_t)(n0 + row) * KD + kt * 64 + c16s * 8;
      async_ld16(src, Bs + f16 * 16);
    }
    __syncthreads();

#pragma unroll
    for (int kk = 0; kk < 2; ++kk) {
      short8_t af[4], bfr[4];
#pragma unroll
      for (int mi = 0; mi < 4; ++mi) {
        int r = wm * 64 + mi * 16 + row16;
        int kb = kk * 128 + kgrp * 32;
        f32x4 lo = *(const f32x4*)(As + r * 256 + (kb ^ ((r & 7) << 4)));
        f32x4 hi = *(const f32x4*)(As + r * 256 + ((kb + 16) ^ ((r & 7) << 4)));
        union { short8_t v; unsigned short u[8]; } pk;
        pk.u[0] = f2bf(lo[0]); pk.u[1] = f2bf(lo[1]);
        pk.u[2] = f2bf(lo[2]); pk.u[3] = f2bf(lo[3]);
        pk.u[4] = f2bf(hi[0]); pk.u[5] = f2bf(hi[1]);
        pk.u[6] = f2bf(hi[2]); pk.u[7] = f2bf(hi[3]);
        af[mi] = pk.v;
      }
#pragma unroll
      for (int ni = 0; ni < 4; ++ni) {
        int r = wn * 64 + ni * 16 + row16;
        int kb = kk * 64 + kgrp * 16;
        bfr[ni] = *(const short8_t*)(Bs + r * 128 + (kb ^ ((r & 7) << 4)));
      }
#pragma unroll
      for (int mi = 0; mi < 4; ++mi)
#pragma unroll
        for (int ni = 0; ni < 4; ++ni)
          acc[mi][ni] = __builtin_amdgcn_mfma_f32_16x16x32_bf16(
              af[mi], bfr[ni], acc[mi][ni], 0, 0, 0);
    }
  }

#pragma unroll
  for (int mi = 0; mi < 4; ++mi) {
    size_t grow = m0 + (size_t)(wm * 64 + mi * 16 + kgrp * 4);
#pragma unroll
    for (int ni = 0; ni < 4; ++ni) {
      int col = n0 + wn * 64 + ni * 16 + row16;
      float bia = biasp[col];
      float* op = out + grow * DM + col;
#pragma unroll
      for (int r = 0; r < 4; ++r) op[(size_t)r * DM] = acc[mi][ni][r] + bia;
    }
  }
}

// ------- pass 2a: grouped (d%7) RMS norm, bf16 y in ws -> f32 out ---------
__global__ __launch_bounds__(256) void norm_bf16(const unsigned short* __restrict__ yb,
                                                 const float* __restrict__ gamma,
                                                 float* __restrict__ out) {
  const int tid = threadIdx.x, lane = tid & 63, wv = tid >> 6;
  const size_t row = (size_t)blockIdx.x * 4 + wv;   // one wave per row
  const uint4* rp = (const uint4*)(yb + row * DM);  // 128 x 16B per row
  uint4 p0 = rp[lane * 2], p1 = rp[lane * 2 + 1];   // 16 bf16 per lane
  float v[16];
  const uint32_t w[8] = {p0.x, p0.y, p0.z, p0.w, p1.x, p1.y, p1.z, p1.w};
#pragma unroll
  for (int i = 0; i < 8; ++i) {
    v[2 * i]     = bf2f((unsigned short)(w[i] & 0xffffu));
    v[2 * i + 1] = bf2f((unsigned short)(w[i] >> 16));
  }

  float ss[7] = {0.f, 0.f, 0.f, 0.f, 0.f, 0.f, 0.f};
#pragma unroll
  for (int i = 0; i < 16; ++i) {
    int d = lane * 16 + i;
    int g = d % 7;
    float sq = v[i] * v[i];
#pragma unroll
    for (int t = 0; t < 7; ++t) ss[t] += (g == t) ? sq : 0.f;
  }
#pragma unroll
  for (int t = 0; t < 7; ++t) {
#pragma unroll
    for (int off = 32; off >= 1; off >>= 1) ss[t] += __shfl_xor(ss[t], off, 64);
  }
  float inv[7];
#pragma unroll
  for (int t = 0; t < 7; ++t) {
    float cnt = (t < 2) ? 147.f : 146.f;   // D=1024: groups 0,1 have 147 dims
    inv[t] = rsqrtf(ss[t] / cnt + 1e-6f);
  }
  float* op = out + row * DM + lane * 16;
  const float* gp = gamma + lane * 16;
#pragma unroll
  for (int q = 0; q < 4; ++q) {
    float4 o4;
    float tmp[4];
#pragma unroll
    for (int i = 0; i < 4; ++i) {
      int d = lane * 16 + q * 4 + i;
      int g = d % 7;
      float iv = inv[0];
#pragma unroll
      for (int t = 1; t < 7; ++t) iv = (g == t) ? inv[t] : iv;
      tmp[i] = v[q * 4 + i] * iv * gp[q * 4 + i];
    }
    o4.x = tmp[0]; o4.y = tmp[1]; o4.z = tmp[2]; o4.w = tmp[3];
    *(float4*)(op + q * 4) = o4;
  }
}

// ------- pass 2b: grouped (d%7) RMS norm, f32 in-place (fallback) ---------
__global__ __launch_bounds__(256) void norm_kernel(float* __restrict__ y,
                                                   const float* __restrict__ gamma) {
  const int tid = threadIdx.x, lane = tid & 63, wv = tid >> 6;
  const size_t row = (size_t)blockIdx.x * 4 + wv;   // one wave per row
  float4* rp = (float4*)(y + row * DM);
  const float4* gp = (const float4*)gamma;
  float4 v[4];
#pragma unroll
  for (int jj = 0; jj < 4; ++jj) v[jj] = rp[jj * 64 + lane];

  float ss[7] = {0.f, 0.f, 0.f, 0.f, 0.f, 0.f, 0.f};
#pragma unroll
  for (int jj = 0; jj < 4; ++jj) {
    const float vv[4] = {v[jj].x, v[jj].y, v[jj].z, v[jj].w};
#pragma unroll
    for (int i = 0; i < 4; ++i) {
      int d = (jj * 64 + lane) * 4 + i;
      int g = d % 7;
      float sq = vv[i] * vv[i];
#pragma unroll
      for (int t = 0; t < 7; ++t) ss[t] += (g == t) ? sq : 0.f;
    }
  }
#pragma unroll
  for (int t = 0; t < 7; ++t) {
#pragma unroll
    for (int off = 32; off >= 1; off >>= 1) ss[t] += __shfl_xor(ss[t], off, 64);
  }
  float inv[7];
#pragma unroll
  for (int t = 0; t < 7; ++t) {
    float cnt = (t < 2) ? 147.f : 146.f;
    inv[t] = rsqrtf(ss[t] / cnt + 1e-6f);
  }
#pragma unroll
  for (int jj = 0; jj < 4; ++jj) {
    float4 g4 = gp[jj * 64 + lane];
    const float vv[4] = {v[jj].x, v[jj].y, v[jj].z, v[jj].w};
    const float gg[4] = {g4.x, g4.y, g4.z, g4.w};
    float o[4];
#pragma unroll
    for (int i = 0; i < 4; ++i) {
      int d = (jj * 64 + lane) * 4 + i;
      int g = d % 7;
      float iv = inv[0];
#pragma unroll
      for (int t = 1; t < 7; ++t) iv = (g == t) ? inv[t] : iv;
      o[i] = vv[i] * iv * gg[i];
    }
    rp[jj * 64 + lane] = make_float4(o[0], o[1], o[2], o[3]);
  }
}

extern "C" void kernel_launch(void* const* d_in, const int* in_sizes, int n_in,
                              void* d_out, int out_size, void* d_ws, size_t ws_size,
                              hipStream_t stream) {
  const float* x     = (const float*)d_in[0];
  const float* W     = (const float*)d_in[1];
  const float* b     = (const float*)d_in[2];
  const float* theta = (const float*)d_in[3];
  const float* gamma = (const float*)d_in[4];
  float* out = (float*)d_out;
  (void)in_sizes; (void)n_in; (void)out_size;

  char* ws = (char*)d_ws;
  unsigned short* Wt = (unsigned short*)ws;                 // 6,291,456 B
  float* biasp = (float*)(ws + 6291456);                    // 4 KiB
  float* zp    = (float*)(ws + 6291456 + 4096);             // 4 KiB zeros
  unsigned short* xbp = (unsigned short*)(ws + 6299648);
  const size_t needA = 6299648 + (size_t)NB * 8194 * DM * 2;
  unsigned short* yb = (unsigned short*)(ws + needA);       // 67,108,864 B
  const size_t needB = needA + (size_t)NB * SEQ * DM * 2;

  if (ws_size >= needB) {
    prep_all<<<dim3(769 + 4096), dim3(256), 0, stream>>>(
        x, W, b, theta, xbp, Wt, biasp, zp);
    gemm256<1><<<dim3(512), dim3(1024), 0, stream>>>(xbp, Wt, biasp, yb);
    norm_bf16<<<dim3(8192), dim3(256), 0, stream>>>(yb, gamma, out);
  } else if (ws_size >= needA) {
    prep_all<<<dim3(769 + 4096), dim3(256), 0, stream>>>(
        x, W, b, theta, xbp, Wt, biasp, zp);
    gemm256<0><<<dim3(512), dim3(1024), 0, stream>>>(xbp, Wt, biasp, out);
    norm_kernel<<<dim3(8192), dim3(256), 0, stream>>>(out, gamma);
  } else {
    prep_all<<<dim3(769), dim3(256), 0, stream>>>(
        x, W, b, theta, (unsigned short*)zp, Wt, biasp, zp);
    gemm_fb<<<dim3(2048), dim3(256), 0, stream>>>(x, Wt, biasp, zp, out);
    norm_kernel<<<dim3(8192), dim3(256), 0, stream>>>(out, gamma);
  }
}

// Round 16
// 254.787 us; speedup vs baseline: 1.0005x; 1.0005x over previous
//
#include <hip/hip_runtime.h>
#include <hip/hip_bf16.h>
#include <stdint.h>

// eidosNeighborMixer on MI355X:
//   pass 0 (prep_all, fused): W' = rotate(W, theta0+theta1) -> Wt[N][K] bf16;
//            b' = rotate(b) + zero page; xbp = bf16(x) seq-padded.
//   pass 1 : GEMM  out = A @ Wt^T + b'   (A[m,k] = xbp[b][s + k/1024][k%1024])
//            R9 structure (measured best): 256x256 tile, BK=32, 16 waves
//            (4Mx4N, 1024 thr), wave 64x64 (acc 64 VGPR -> 4 waves/SIMD TLP),
//            4-deep LDS ring, global_load_lds staging, XOR chunk swizzle
//            (conflicts 0), counted vmcnt(4), lgkm(0)+setprio MFMA cluster.
//            56% MfmaUtil = ~90% of the 64x64-tile LDS-read-BW floor
//            (160 KiB/kt / 85 B/cyc = 1928 cyc vs 2162 measured).
//            Epilogue writes y as BF16 to ws (halves write traffic).
//   pass 2 : grouped (d%7) RMS norm: reads bf16 y (dense ushort4/lane),
//            writes f32 out (dense float4/lane) — norm_kernel's coalesced
//            lane layout (R15's 16-consec-elem layout had 1/4-density stores).

#define SEQ 8192
#define NB 4
#define DM 1024
#define KD 3072

typedef __attribute__((ext_vector_type(8))) short short8_t;
typedef __attribute__((ext_vector_type(4))) float f32x4;

__device__ __forceinline__ unsigned short f2bf(float f) {
  union { float f; uint32_t u; } v; v.f = f;
  return (unsigned short)((v.u + 0x7fffu + ((v.u >> 16) & 1u)) >> 16);  // RNE
}

__device__ __forceinline__ float bf2f(unsigned short u) {
  union { uint32_t u; float f; } v; v.u = (uint32_t)u << 16;
  return v.f;
}

__device__ __forceinline__ void async_ld16(const void* g, void* l) {
  __builtin_amdgcn_global_load_lds(
      (const __attribute__((address_space(1))) uint32_t*)g,
      (__attribute__((address_space(3))) uint32_t*)(uint32_t)(uintptr_t)l,
      16, 0, 0);
}

// -------- prep_all: blocks 0..767 = W rotate+transpose; 768 = bias+zp;
//          769.. = x -> bf16 seq-padded (grid-stride) --------------------
__global__ __launch_bounds__(256) void prep_all(const float* __restrict__ x,
                                                const float* __restrict__ W,
                                                const float* __restrict__ b,
                                                const float* __restrict__ theta,
                                                unsigned short* __restrict__ xbp,
                                                unsigned short* __restrict__ Wt,
                                                float* __restrict__ biasp,
                                                float* __restrict__ zp) {
  const int B0 = blockIdx.x;
  const int t = threadIdx.x;
  if (B0 < 768) {
    __shared__ float csc[32], css[32];
    __shared__ unsigned short tile[64][72];  // [n_local][k_local], padded
    const int bk = B0 % 48, bn = B0 / 48;
    const int k0 = bk * 64, n0 = bn * 64;
    if (t < 32) {
      int d = n0 / 2 + t;
      float ang = theta[d] + theta[512 + d];
      csc[t] = cosf(ang); css[t] = sinf(ang);
    }
    __syncthreads();
#pragma unroll
    for (int i = 0; i < 8; ++i) {
      int idx = i * 256 + t;           // 2048 pairs = 64 k-rows x 32 pairs
      int pr = idx >> 5;               // k row 0..63
      int pc = idx & 31;               // pair col 0..31
      const float2 w2 = *(const float2*)&W[(size_t)(k0 + pr) * DM + n0 + pc * 2];
      float c = csc[pc], s = css[pc];
      tile[pc * 2][pr]     = f2bf(w2.x * c - w2.y * s);
      tile[pc * 2 + 1][pr] = f2bf(w2.x * s + w2.y * c);
    }
    __syncthreads();
#pragma unroll
    for (int i = 0; i < 16; ++i) {
      int idx = i * 256 + t;           // 4096 elems
      int r = idx >> 6, cdx = idx & 63;
      Wt[(size_t)(n0 + r) * KD + k0 + cdx] = tile[r][cdx];
    }
  } else if (B0 == 768) {
#pragma unroll
    for (int p = t; p < 512; p += 256) {
      float ang = theta[p] + theta[512 + p];
      float c = cosf(ang), s = sinf(ang);
      float be = b[2 * p], bo = b[2 * p + 1];
      biasp[2 * p]     = be * c - bo * s;
      biasp[2 * p + 1] = be * s + bo * c;
    }
    ((float4*)zp)[t] = make_float4(0.f, 0.f, 0.f, 0.f);
  } else {
    const size_t total = (size_t)NB * 8194 * 128;  // 16B chunks (8 bf16)
    const size_t nxb = (size_t)(gridDim.x - 769) * 256;
    for (size_t i = (size_t)(B0 - 769) * 256 + t; i < total; i += nxb) {
      int d8 = (int)(i & 127);
      size_t rem = i >> 7;
      int sp = (int)(rem % 8194);
      size_t bb = rem / 8194;
      uint4 o = make_uint4(0u, 0u, 0u, 0u);
      if (sp > 0 && sp < 8193) {
        const float4* src =
            (const float4*)(x + (bb * SEQ + (size_t)(sp - 1)) * DM + d8 * 8);
        float4 lo = src[0], hi = src[1];
        o.x = (uint32_t)f2bf(lo.x) | ((uint32_t)f2bf(lo.y) << 16);
        o.y = (uint32_t)f2bf(lo.z) | ((uint32_t)f2bf(lo.w) << 16);
        o.z = (uint32_t)f2bf(hi.x) | ((uint32_t)f2bf(hi.y) << 16);
        o.w = (uint32_t)f2bf(hi.z) | ((uint32_t)f2bf(hi.w) << 16);
      }
      ((uint4*)xbp)[i] = o;
    }
  }
}

// ---- GEMM: 256x256, BK=32, 16 waves x (64x64), 4-ring, TLP-overlap (R9) ---
// BF16OUT=1: write bf16 y to ws. BF16OUT=0: write f32 (+bias) to out.
template <int BF16OUT>
__global__ __launch_bounds__(1024, 4) void gemm256(const unsigned short* __restrict__ xbp,
                                                   const unsigned short* __restrict__ Wt,
                                                   const float* __restrict__ biasp,
                                                   void* __restrict__ outp) {
  __shared__ __align__(16) unsigned char As[4][16384];  // [buf][256 rows][32 bf16]
  __shared__ __align__(16) unsigned char Bs[4][16384];  // [buf][256 nrow][32 bf16]

  const int tid = threadIdx.x;
  const int lane = tid & 63;
  const int wid = tid >> 6;                   // 0..15
  const int wm = wid >> 2, wn = wid & 3;      // 4M x 4N wave grid
  const int row16 = lane & 15, kgrp = lane >> 4;

  // XCD-bijective swizzle: 512 blocks = 8 XCD x (16 mtiles x 4 ntiles)
  const int L = blockIdx.x;
  const int xcd = L & 7;
  const int j = L >> 3;
  const int mtile = xcd * 16 + (j >> 2);
  const int ntile = j & 3;

  const int n0 = ntile * 256;
  const int batch = mtile >> 5;
  const int s0 = (mtile & 31) * 256;
  const size_t m0 = (size_t)mtile * 256;

  // fragment LDS byte offsets within a 16 KiB buffer (thread-constant)
  int aoff[4], boff[4];
#pragma unroll
  for (int mi = 0; mi < 4; ++mi) {
    int r = wm * 64 + mi * 16 + row16;
    aoff[mi] = r * 64 + (kgrp ^ ((r >> 1) & 3)) * 16;
  }
#pragma unroll
  for (int ni = 0; ni < 4; ++ni) {
    int r = wn * 64 + ni * 16 + row16;
    boff[ni] = r * 64 + (kgrp ^ ((r >> 1) & 3)) * 16;
  }

  // staging: 1024 threads, 1 load each per matrix per K-tile.
  // LDS dest LINEAR; global source chunk pre-swizzled (same XOR as reads).
  const int srow = tid >> 2, sc16 = tid & 3;
  const int scs = sc16 ^ ((srow >> 1) & 3);
  auto stageA = [&](int kt, int buf) {
    const int c = kt >> 5;
    const int ksb = (kt & 31) * 32;
    const size_t base = ((size_t)batch * 8194 + (size_t)(s0 + c)) * DM + ksb;
    async_ld16(xbp + base + (size_t)srow * DM + scs * 8, &As[buf][tid * 16]);
  };
  auto stageB = [&](int kt, int buf) {
    const int kb = kt * 32;
    async_ld16(Wt + (size_t)(n0 + srow) * KD + kb + scs * 8, &Bs[buf][tid * 16]);
  };

  f32x4 acc[4][4];
#pragma unroll
  for (int a = 0; a < 4; ++a)
#pragma unroll
    for (int b = 0; b < 4; ++b) acc[a][b] = (f32x4){0.f, 0.f, 0.f, 0.f};

  // prologue: stage kt 0,1,2 (2 loads each); confirm stage(0); barrier
  stageA(0, 0); stageB(0, 0);
  stageA(1, 1); stageB(1, 1);
  stageA(2, 2); stageB(2, 2);
  asm volatile("s_waitcnt vmcnt(4)" ::: "memory");
  __builtin_amdgcn_s_barrier();

  // per K-tile: stage kt+3, read own 8 frags, lgkm(0) (TLP hides the drain),
  // 16 MFMA under setprio, counted vmcnt, barrier.
  auto body = [&](int kt, int buf, int doStage, int vmN) {
    const int sbuf = (buf + 3) & 3;
    if (doStage) { stageA(kt + 3, sbuf); stageB(kt + 3, sbuf); }
    short8_t af[4], bf[4];
#pragma unroll
    for (int mi = 0; mi < 4; ++mi)
      af[mi] = *(const short8_t*)(&As[buf][0] + aoff[mi]);
#pragma unroll
    for (int ni = 0; ni < 4; ++ni)
      bf[ni] = *(const short8_t*)(&Bs[buf][0] + boff[ni]);
    asm volatile("s_waitcnt lgkmcnt(0)" ::: "memory");
    __builtin_amdgcn_sched_barrier(0);
    __builtin_amdgcn_s_setprio(1);
#pragma unroll
    for (int mi = 0; mi < 4; ++mi)
#pragma unroll
      for (int ni = 0; ni < 4; ++ni)
        acc[mi][ni] = __builtin_amdgcn_mfma_f32_16x16x32_bf16(
            af[mi], bf[ni], acc[mi][ni], 0, 0, 0);
    __builtin_amdgcn_s_setprio(0);
    if (vmN == 4)      asm volatile("s_waitcnt vmcnt(4)" ::: "memory");
    else if (vmN == 2) asm volatile("s_waitcnt vmcnt(2)" ::: "memory");
    else               asm volatile("s_waitcnt vmcnt(0)" ::: "memory");
    __builtin_amdgcn_sched_barrier(0);
    __builtin_amdgcn_s_barrier();
  };

  for (int kt4 = 0; kt4 < 92; kt4 += 4) {
    body(kt4 + 0, 0, 1, 4);
    body(kt4 + 1, 1, 1, 4);
    body(kt4 + 2, 2, 1, 4);
    body(kt4 + 3, 3, 1, 4);
  }
  // tail: kt92 stages kt95; then counted drains per the FIFO ledger
  body(92, 0, 1, 4);
  body(93, 1, 0, 2);
  body(94, 2, 0, 0);
  body(95, 3, 0, 0);

  // epilogue: C[row=kgrp*4+r, col=row16] per 16x16 fragment
#pragma unroll
  for (int mi = 0; mi < 4; ++mi) {
    size_t grow = m0 + (size_t)(wm * 64 + mi * 16 + kgrp * 4);
#pragma unroll
    for (int ni = 0; ni < 4; ++ni) {
      int col = n0 + wn * 64 + ni * 16 + row16;
      float bia = biasp[col];
      if constexpr (BF16OUT) {
        unsigned short* op = (unsigned short*)outp + grow * DM + col;
#pragma unroll
        for (int r = 0; r < 4; ++r) op[(size_t)r * DM] = f2bf(acc[mi][ni][r] + bia);
      } else {
        float* op = (float*)outp + grow * DM + col;
#pragma unroll
        for (int r = 0; r < 4; ++r) op[(size_t)r * DM] = acc[mi][ni][r] + bia;
      }
    }
  }
}

// ---------------- fallback GEMM (fp32 A direct), 128x128 2-barrier ----------
__global__ __launch_bounds__(256) void gemm_fb(const float* __restrict__ Ag,
                                               const unsigned short* __restrict__ Wt,
                                               const float* __restrict__ biasp,
                                               const float* __restrict__ zp,
                                               float* __restrict__ out) {
  __shared__ __align__(16) unsigned char As[128 * 64 * 4];
  __shared__ __align__(16) unsigned char Bs[128 * 64 * 2];

  const int tid = threadIdx.x;
  const int lane = tid & 63;
  const int wid = tid >> 6;
  const int wm = wid >> 1, wn = wid & 1;
  const int row16 = lane & 15, kgrp = lane >> 4;

  const int L = blockIdx.x;
  const int xcd = L & 7;
  const int j = L >> 3;
  const int mtile = xcd * 32 + (j >> 3);
  const int ntile = j & 7;

  const int n0 = ntile * 128;
  const int batch = mtile >> 6;
  const int s0 = (mtile & 63) * 128;
  const size_t m0 = (size_t)mtile * 128;

  f32x4 acc[4][4];
#pragma unroll
  for (int a = 0; a < 4; ++a)
#pragma unroll
    for (int b = 0; b < 4; ++b) acc[a][b] = (f32x4){0.f, 0.f, 0.f, 0.f};

  for (int kt = 0; kt < 48; ++kt) {
    const int c = kt >> 4;
    const int ksb = (kt & 15) * 64;
    __syncthreads();
#pragma unroll
    for (int it = 0; it < 8; ++it) {
      int f16 = it * 256 + tid;
      int row = f16 >> 4, c16 = f16 & 15;
      int c16s = c16 ^ (row & 7);
      int s = s0 + row + c - 1;
      const float* src = (s >= 0 && s < SEQ)
          ? Ag + ((size_t)batch * SEQ + (size_t)s) * DM + ksb + c16s * 4
          : zp + c16s * 4;
      async_ld16(src, As + f16 * 16);
    }
#pragma unroll
    for (int it = 0; it < 4; ++it) {
      int f16 = it * 256 + tid;
      int row = f16 >> 3, c16 = f16 & 7;
      int c16s = c16 ^ (row & 7);
      const unsigned short* src = Wt + (size_t)(n0 + row) * KD + kt * 64 + c16s * 8;
      async_ld16(src, Bs + f16 * 16);
    }
    __syncthreads();

#pragma unroll
    for (int kk = 0; kk < 2; ++kk) {
      short8_t af[4], bfr[4];
#pragma unroll
      for (int mi = 0; mi < 4; ++mi) {
        int r = wm * 64 + mi * 16 + row16;
        int kb = kk * 128 + kgrp * 32;
        f32x4 lo = *(const f32x4*)(As + r * 256 + (kb ^ ((r & 7) << 4)));
        f32x4 hi = *(const f32x4*)(As + r * 256 + ((kb + 16) ^ ((r & 7) << 4)));
        union { short8_t v; unsigned short u[8]; } pk;
        pk.u[0] = f2bf(lo[0]); pk.u[1] = f2bf(lo[1]);
        pk.u[2] = f2bf(lo[2]); pk.u[3] = f2bf(lo[3]);
        pk.u[4] = f2bf(hi[0]); pk.u[5] = f2bf(hi[1]);
        pk.u[6] = f2bf(hi[2]); pk.u[7] = f2bf(hi[3]);
        af[mi] = pk.v;
      }
#pragma unroll
      for (int ni = 0; ni < 4; ++ni) {
        int r = wn * 64 + ni * 16 + row16;
        int kb = kk * 64 + kgrp * 16;
        bfr[ni] = *(const short8_t*)(Bs + r * 128 + (kb ^ ((r & 7) << 4)));
      }
#pragma unroll
      for (int mi = 0; mi < 4; ++mi)
#pragma unroll
        for (int ni = 0; ni < 4; ++ni)
          acc[mi][ni] = __builtin_amdgcn_mfma_f32_16x16x32_bf16(
              af[mi], bfr[ni], acc[mi][ni], 0, 0, 0);
    }
  }

#pragma unroll
  for (int mi = 0; mi < 4; ++mi) {
    size_t grow = m0 + (size_t)(wm * 64 + mi * 16 + kgrp * 4);
#pragma unroll
    for (int ni = 0; ni < 4; ++ni) {
      int col = n0 + wn * 64 + ni * 16 + row16;
      float bia = biasp[col];
      float* op = out + grow * DM + col;
#pragma unroll
      for (int r = 0; r < 4; ++r) op[(size_t)r * DM] = acc[mi][ni][r] + bia;
    }
  }
}

// ------- pass 2a: grouped (d%7) RMS norm, bf16 y -> f32 out (dense) -------
__global__ __launch_bounds__(256) void norm_bf16(const unsigned short* __restrict__ yb,
                                                 const float* __restrict__ gamma,
                                                 float* __restrict__ out) {
  const int tid = threadIdx.x, lane = tid & 63, wv = tid >> 6;
  const size_t row = (size_t)blockIdx.x * 4 + wv;   // one wave per row
  const ushort4* rp = (const ushort4*)(yb + row * DM);  // 256 x 8B per row
  const float4* gp = (const float4*)gamma;
  float v[4][4];
#pragma unroll
  for (int jj = 0; jj < 4; ++jj) {
    ushort4 u = rp[jj * 64 + lane];                 // dense: 8 B/lane
    v[jj][0] = bf2f(u.x); v[jj][1] = bf2f(u.y);
    v[jj][2] = bf2f(u.z); v[jj][3] = bf2f(u.w);
  }

  float ss[7] = {0.f, 0.f, 0.f, 0.f, 0.f, 0.f, 0.f};
#pragma unroll
  for (int jj = 0; jj < 4; ++jj) {
#pragma unroll
    for (int i = 0; i < 4; ++i) {
      int d = (jj * 64 + lane) * 4 + i;
      int g = d % 7;
      float sq = v[jj][i] * v[jj][i];
#pragma unroll
      for (int t = 0; t < 7; ++t) ss[t] += (g == t) ? sq : 0.f;
    }
  }
#pragma unroll
  for (int t = 0; t < 7; ++t) {
#pragma unroll
    for (int off = 32; off >= 1; off >>= 1) ss[t] += __shfl_xor(ss[t], off, 64);
  }
  float inv[7];
#pragma unroll
  for (int t = 0; t < 7; ++t) {
    float cnt = (t < 2) ? 147.f : 146.f;   // D=1024: groups 0,1 have 147 dims
    inv[t] = rsqrtf(ss[t] / cnt + 1e-6f);
  }
  float4* op = (float4*)(out + row * DM);
#pragma unroll
  for (int jj = 0; jj < 4; ++jj) {
    float4 g4 = gp[jj * 64 + lane];
    const float gg[4] = {g4.x, g4.y, g4.z, g4.w};
    float o[4];
#pragma unroll
    for (int i = 0; i < 4; ++i) {
      int d = (jj * 64 + lane) * 4 + i;
      int g = d % 7;
      float iv = inv[0];
#pragma unroll
      for (int t = 1; t < 7; ++t) iv = (g == t) ? inv[t] : iv;
      o[i] = v[jj][i] * iv * gg[i];
    }
    op[jj * 64 + lane] = make_float4(o[0], o[1], o[2], o[3]);  // dense store
  }
}

// ------- pass 2b: grouped (d%7) RMS norm, f32 in-place (fallback) ---------
__global__ __launch_bounds__(256) void norm_kernel(float* __restrict__ y,
                                                   const float* __restrict__ gamma) {
  const int tid = threadIdx.x, lane = tid & 63, wv = tid >> 6;
  const size_t row = (size_t)blockIdx.x * 4 + wv;   // one wave per row
  float4* rp = (float4*)(y + row * DM);
  const float4* gp = (const float4*)gamma;
  float4 v[4];
#pragma unroll
  for (int jj = 0; jj < 4; ++jj) v[jj] = rp[jj * 64 + lane];

  float ss[7] = {0.f, 0.f, 0.f, 0.f, 0.f, 0.f, 0.f};
#pragma unroll
  for (int jj = 0; jj < 4; ++jj) {
    const float vv[4] = {v[jj].x, v[jj].y, v[jj].z, v[jj].w};
#pragma unroll
    for (int i = 0; i < 4; ++i) {
      int d = (jj * 64 + lane) * 4 + i;
      int g = d % 7;
      float sq = vv[i] * vv[i];
#pragma unroll
      for (int t = 0; t < 7; ++t) ss[t] += (g == t) ? sq : 0.f;
    }
  }
#pragma unroll
  for (int t = 0; t < 7; ++t) {
#pragma unroll
    for (int off = 32; off >= 1; off >>= 1) ss[t] += __shfl_xor(ss[t], off, 64);
  }
  float inv[7];
#pragma unroll
  for (int t = 0; t < 7; ++t) {
    float cnt = (t < 2) ? 147.f : 146.f;
    inv[t] = rsqrtf(ss[t] / cnt + 1e-6f);
  }
#pragma unroll
  for (int jj = 0; jj < 4; ++jj) {
    float4 g4 = gp[jj * 64 + lane];
    const float vv[4] = {v[jj].x, v[jj].y, v[jj].z, v[jj].w};
    const float gg[4] = {g4.x, g4.y, g4.z, g4.w};
    float o[4];
#pragma unroll
    for (int i = 0; i < 4; ++i) {
      int d = (jj * 64 + lane) * 4 + i;
      int g = d % 7;
      float iv = inv[0];
#pragma unroll
      for (int t = 1; t < 7; ++t) iv = (g == t) ? inv[t] : iv;
      o[i] = vv[i] * iv * gg[i];
    }
    rp[jj * 64 + lane] = make_float4(o[0], o[1], o[2], o[3]);
  }
}

extern "C" void kernel_launch(void* const* d_in, const int* in_sizes, int n_in,
                              void* d_out, int out_size, void* d_ws, size_t ws_size,
                              hipStream_t stream) {
  const float* x     = (const float*)d_in[0];
  const float* W     = (const float*)d_in[1];
  const float* b     = (const float*)d_in[2];
  const float* theta = (const float*)d_in[3];
  const float* gamma = (const float*)d_in[4];
  float* out = (float*)d_out;
  (void)in_sizes; (void)n_in; (void)out_size;

  char* ws = (char*)d_ws;
  unsigned short* Wt = (unsigned short*)ws;                 // 6,291,456 B
  float* biasp = (float*)(ws + 6291456);                    // 4 KiB
  float* zp    = (float*)(ws + 6291456 + 4096);             // 4 KiB zeros
  unsigned short* xbp = (unsigned short*)(ws + 6299648);
  const size_t needA = 6299648 + (size_t)NB * 8194 * DM * 2;
  unsigned short* yb = (unsigned short*)(ws + needA);       // 67,108,864 B
  const size_t needB = needA + (size_t)NB * SEQ * DM * 2;

  if (ws_size >= needB) {
    prep_all<<<dim3(769 + 4096), dim3(256), 0, stream>>>(
        x, W, b, theta, xbp, Wt, biasp, zp);
    gemm256<1><<<dim3(512), dim3(1024), 0, stream>>>(xbp, Wt, biasp, yb);
    norm_bf16<<<dim3(8192), dim3(256), 0, stream>>>(yb, gamma, out);
  } else if (ws_size >= needA) {
    prep_all<<<dim3(769 + 4096), dim3(256), 0, stream>>>(
        x, W, b, theta, xbp, Wt, biasp, zp);
    gemm256<0><<<dim3(512), dim3(1024), 0, stream>>>(xbp, Wt, biasp, out);
    norm_kernel<<<dim3(8192), dim3(256), 0, stream>>>(out, gamma);
  } else {
    prep_all<<<dim3(769), dim3(256), 0, stream>>>(
        x, W, b, theta, (unsigned short*)zp, Wt, biasp, zp);
    gemm_fb<<<dim3(2048), dim3(256), 0, stream>>>(x, Wt, biasp, zp, out);
    norm_kernel<<<dim3(8192), dim3(256), 0, stream>>>(out, gamma);
  }
}

// Round 17
// 253.129 us; speedup vs baseline: 1.0071x; 1.0066x over previous
//
#include <hip/hip_runtime.h>
#include <hip/hip_bf16.h>
#include <stdint.h>

// eidosNeighborMixer on MI355X — FINAL (R14 configuration, best measured):
//   pass 0 (prep_all, fused): W' = rotate(W, theta0+theta1) -> Wt[N][K] bf16;
//            b' = rotate(b) + zero page; xbp = bf16(x) seq-padded.
//   pass 1 : GEMM  out = A @ Wt^T + b'   (A[m,k] = xbp[b][s + k/1024][k%1024])
//            256x256 tile, BK=32, 16 waves (4Mx4N, 1024 thr), wave 64x64
//            (acc 64 VGPR -> 4 waves/SIMD TLP), 4-deep LDS ring,
//            global_load_lds staging, XOR chunk swizzle (conflicts 0),
//            counted vmcnt(4), lgkm(0)+setprio MFMA cluster.
//            54-56% MfmaUtil = ~85% of the 64x64-tile LDS-read-BW ceiling
//            (MFMA 1242 cyc vs LDS 1882 cyc/kt -> 66% max for this tiling).
//   pass 2 : grouped (d%7) RMS norm, f32 in-place on d_out.
//   (bf16-intermediate variant measured NEUTRAL: y is L3-resident, so the
//    DRAM saving was already absorbed by Infinity Cache.)

#define SEQ 8192
#define NB 4
#define DM 1024
#define KD 3072

typedef __attribute__((ext_vector_type(8))) short short8_t;
typedef __attribute__((ext_vector_type(4))) float f32x4;

__device__ __forceinline__ unsigned short f2bf(float f) {
  union { float f; uint32_t u; } v; v.f = f;
  return (unsigned short)((v.u + 0x7fffu + ((v.u >> 16) & 1u)) >> 16);  // RNE
}

__device__ __forceinline__ void async_ld16(const void* g, void* l) {
  __builtin_amdgcn_global_load_lds(
      (const __attribute__((address_space(1))) uint32_t*)g,
      (__attribute__((address_space(3))) uint32_t*)(uint32_t)(uintptr_t)l,
      16, 0, 0);
}

// -------- prep_all: blocks 0..767 = W rotate+transpose; 768 = bias+zp;
//          769.. = x -> bf16 seq-padded (grid-stride) --------------------
__global__ __launch_bounds__(256) void prep_all(const float* __restrict__ x,
                                                const float* __restrict__ W,
                                                const float* __restrict__ b,
                                                const float* __restrict__ theta,
                                                unsigned short* __restrict__ xbp,
                                                unsigned short* __restrict__ Wt,
                                                float* __restrict__ biasp,
                                                float* __restrict__ zp) {
  const int B0 = blockIdx.x;
  const int t = threadIdx.x;
  if (B0 < 768) {
    __shared__ float csc[32], css[32];
    __shared__ unsigned short tile[64][72];  // [n_local][k_local], padded
    const int bk = B0 % 48, bn = B0 / 48;
    const int k0 = bk * 64, n0 = bn * 64;
    if (t < 32) {
      int d = n0 / 2 + t;
      float ang = theta[d] + theta[512 + d];
      csc[t] = cosf(ang); css[t] = sinf(ang);
    }
    __syncthreads();
#pragma unroll
    for (int i = 0; i < 8; ++i) {
      int idx = i * 256 + t;           // 2048 pairs = 64 k-rows x 32 pairs
      int pr = idx >> 5;               // k row 0..63
      int pc = idx & 31;               // pair col 0..31
      const float2 w2 = *(const float2*)&W[(size_t)(k0 + pr) * DM + n0 + pc * 2];
      float c = csc[pc], s = css[pc];
      tile[pc * 2][pr]     = f2bf(w2.x * c - w2.y * s);
      tile[pc * 2 + 1][pr] = f2bf(w2.x * s + w2.y * c);
    }
    __syncthreads();
#pragma unroll
    for (int i = 0; i < 16; ++i) {
      int idx = i * 256 + t;           // 4096 elems
      int r = idx >> 6, cdx = idx & 63;
      Wt[(size_t)(n0 + r) * KD + k0 + cdx] = tile[r][cdx];
    }
  } else if (B0 == 768) {
#pragma unroll
    for (int p = t; p < 512; p += 256) {
      float ang = theta[p] + theta[512 + p];
      float c = cosf(ang), s = sinf(ang);
      float be = b[2 * p], bo = b[2 * p + 1];
      biasp[2 * p]     = be * c - bo * s;
      biasp[2 * p + 1] = be * s + bo * c;
    }
    ((float4*)zp)[t] = make_float4(0.f, 0.f, 0.f, 0.f);
  } else {
    const size_t total = (size_t)NB * 8194 * 128;  // 16B chunks (8 bf16)
    const size_t nxb = (size_t)(gridDim.x - 769) * 256;
    for (size_t i = (size_t)(B0 - 769) * 256 + t; i < total; i += nxb) {
      int d8 = (int)(i & 127);
      size_t rem = i >> 7;
      int sp = (int)(rem % 8194);
      size_t bb = rem / 8194;
      uint4 o = make_uint4(0u, 0u, 0u, 0u);
      if (sp > 0 && sp < 8193) {
        const float4* src =
            (const float4*)(x + (bb * SEQ + (size_t)(sp - 1)) * DM + d8 * 8);
        float4 lo = src[0], hi = src[1];
        o.x = (uint32_t)f2bf(lo.x) | ((uint32_t)f2bf(lo.y) << 16);
        o.y = (uint32_t)f2bf(lo.z) | ((uint32_t)f2bf(lo.w) << 16);
        o.z = (uint32_t)f2bf(hi.x) | ((uint32_t)f2bf(hi.y) << 16);
        o.w = (uint32_t)f2bf(hi.z) | ((uint32_t)f2bf(hi.w) << 16);
      }
      ((uint4*)xbp)[i] = o;
    }
  }
}

// ---- GEMM: 256x256, BK=32, 16 waves x (64x64), 4-ring, TLP-overlap (R9) ---
__global__ __launch_bounds__(1024, 4) void gemm256(const unsigned short* __restrict__ xbp,
                                                   const unsigned short* __restrict__ Wt,
                                                   const float* __restrict__ biasp,
                                                   float* __restrict__ out) {
  __shared__ __align__(16) unsigned char As[4][16384];  // [buf][256 rows][32 bf16]
  __shared__ __align__(16) unsigned char Bs[4][16384];  // [buf][256 nrow][32 bf16]

  const int tid = threadIdx.x;
  const int lane = tid & 63;
  const int wid = tid >> 6;                   // 0..15
  const int wm = wid >> 2, wn = wid & 3;      // 4M x 4N wave grid
  const int row16 = lane & 15, kgrp = lane >> 4;

  // XCD-bijective swizzle: 512 blocks = 8 XCD x (16 mtiles x 4 ntiles)
  const int L = blockIdx.x;
  const int xcd = L & 7;
  const int j = L >> 3;
  const int mtile = xcd * 16 + (j >> 2);
  const int ntile = j & 3;

  const int n0 = ntile * 256;
  const int batch = mtile >> 5;
  const int s0 = (mtile & 31) * 256;
  const size_t m0 = (size_t)mtile * 256;

  // fragment LDS byte offsets within a 16 KiB buffer (thread-constant)
  int aoff[4], boff[4];
#pragma unroll
  for (int mi = 0; mi < 4; ++mi) {
    int r = wm * 64 + mi * 16 + row16;
    aoff[mi] = r * 64 + (kgrp ^ ((r >> 1) & 3)) * 16;
  }
#pragma unroll
  for (int ni = 0; ni < 4; ++ni) {
    int r = wn * 64 + ni * 16 + row16;
    boff[ni] = r * 64 + (kgrp ^ ((r >> 1) & 3)) * 16;
  }

  // staging: 1024 threads, 1 load each per matrix per K-tile.
  // LDS dest LINEAR; global source chunk pre-swizzled (same XOR as reads).
  const int srow = tid >> 2, sc16 = tid & 3;
  const int scs = sc16 ^ ((srow >> 1) & 3);
  auto stageA = [&](int kt, int buf) {
    const int c = kt >> 5;
    const int ksb = (kt & 31) * 32;
    const size_t base = ((size_t)batch * 8194 + (size_t)(s0 + c)) * DM + ksb;
    async_ld16(xbp + base + (size_t)srow * DM + scs * 8, &As[buf][tid * 16]);
  };
  auto stageB = [&](int kt, int buf) {
    const int kb = kt * 32;
    async_ld16(Wt + (size_t)(n0 + srow) * KD + kb + scs * 8, &Bs[buf][tid * 16]);
  };

  f32x4 acc[4][4];
#pragma unroll
  for (int a = 0; a < 4; ++a)
#pragma unroll
    for (int b = 0; b < 4; ++b) acc[a][b] = (f32x4){0.f, 0.f, 0.f, 0.f};

  // prologue: stage kt 0,1,2 (2 loads each); confirm stage(0); barrier
  stageA(0, 0); stageB(0, 0);
  stageA(1, 1); stageB(1, 1);
  stageA(2, 2); stageB(2, 2);
  asm volatile("s_waitcnt vmcnt(4)" ::: "memory");
  __builtin_amdgcn_s_barrier();

  // per K-tile: stage kt+3, read own 8 frags, lgkm(0) (TLP hides the drain),
  // 16 MFMA under setprio, counted vmcnt, barrier.
  auto body = [&](int kt, int buf, int doStage, int vmN) {
    const int sbuf = (buf + 3) & 3;
    if (doStage) { stageA(kt + 3, sbuf); stageB(kt + 3, sbuf); }
    short8_t af[4], bf[4];
#pragma unroll
    for (int mi = 0; mi < 4; ++mi)
      af[mi] = *(const short8_t*)(&As[buf][0] + aoff[mi]);
#pragma unroll
    for (int ni = 0; ni < 4; ++ni)
      bf[ni] = *(const short8_t*)(&Bs[buf][0] + boff[ni]);
    asm volatile("s_waitcnt lgkmcnt(0)" ::: "memory");
    __builtin_amdgcn_sched_barrier(0);
    __builtin_amdgcn_s_setprio(1);
#pragma unroll
    for (int mi = 0; mi < 4; ++mi)
#pragma unroll
      for (int ni = 0; ni < 4; ++ni)
        acc[mi][ni] = __builtin_amdgcn_mfma_f32_16x16x32_bf16(
            af[mi], bf[ni], acc[mi][ni], 0, 0, 0);
    __builtin_amdgcn_s_setprio(0);
    if (vmN == 4)      asm volatile("s_waitcnt vmcnt(4)" ::: "memory");
    else if (vmN == 2) asm volatile("s_waitcnt vmcnt(2)" ::: "memory");
    else               asm volatile("s_waitcnt vmcnt(0)" ::: "memory");
    __builtin_amdgcn_sched_barrier(0);
    __builtin_amdgcn_s_barrier();
  };

  for (int kt4 = 0; kt4 < 92; kt4 += 4) {
    body(kt4 + 0, 0, 1, 4);
    body(kt4 + 1, 1, 1, 4);
    body(kt4 + 2, 2, 1, 4);
    body(kt4 + 3, 3, 1, 4);
  }
  // tail: kt92 stages kt95; then counted drains per the FIFO ledger
  body(92, 0, 1, 4);
  body(93, 1, 0, 2);
  body(94, 2, 0, 0);
  body(95, 3, 0, 0);

  // epilogue: C[row=kgrp*4+r, col=row16] per 16x16 fragment
#pragma unroll
  for (int mi = 0; mi < 4; ++mi) {
    size_t grow = m0 + (size_t)(wm * 64 + mi * 16 + kgrp * 4);
#pragma unroll
    for (int ni = 0; ni < 4; ++ni) {
      int col = n0 + wn * 64 + ni * 16 + row16;
      float bia = biasp[col];
      float* op = out + grow * DM + col;
#pragma unroll
      for (int r = 0; r < 4; ++r) op[(size_t)r * DM] = acc[mi][ni][r] + bia;
    }
  }
}

// ---------------- fallback GEMM (fp32 A direct), 128x128 2-barrier ----------
__global__ __launch_bounds__(256) void gemm_fb(const float* __restrict__ Ag,
                                               const unsigned short* __restrict__ Wt,
                                               const float* __restrict__ biasp,
                                               const float* __restrict__ zp,
                                               float* __restrict__ out) {
  __shared__ __align__(16) unsigned char As[128 * 64 * 4];
  __shared__ __align__(16) unsigned char Bs[128 * 64 * 2];

  const int tid = threadIdx.x;
  const int lane = tid & 63;
  const int wid = tid >> 6;
  const int wm = wid >> 1, wn = wid & 1;
  const int row16 = lane & 15, kgrp = lane >> 4;

  const int L = blockIdx.x;
  const int xcd = L & 7;
  const int j = L >> 3;
  const int mtile = xcd * 32 + (j >> 3);
  const int ntile = j & 7;

  const int n0 = ntile * 128;
  const int batch = mtile >> 6;
  const int s0 = (mtile & 63) * 128;
  const size_t m0 = (size_t)mtile * 128;

  f32x4 acc[4][4];
#pragma unroll
  for (int a = 0; a < 4; ++a)
#pragma unroll
    for (int b = 0; b < 4; ++b) acc[a][b] = (f32x4){0.f, 0.f, 0.f, 0.f};

  for (int kt = 0; kt < 48; ++kt) {
    const int c = kt >> 4;
    const int ksb = (kt & 15) * 64;
    __syncthreads();
#pragma unroll
    for (int it = 0; it < 8; ++it) {
      int f16 = it * 256 + tid;
      int row = f16 >> 4, c16 = f16 & 15;
      int c16s = c16 ^ (row & 7);
      int s = s0 + row + c - 1;
      const float* src = (s >= 0 && s < SEQ)
          ? Ag + ((size_t)batch * SEQ + (size_t)s) * DM + ksb + c16s * 4
          : zp + c16s * 4;
      async_ld16(src, As + f16 * 16);
    }
#pragma unroll
    for (int it = 0; it < 4; ++it) {
      int f16 = it * 256 + tid;
      int row = f16 >> 3, c16 = f16 & 7;
      int c16s = c16 ^ (row & 7);
      const unsigned short* src = Wt + (size_t)(n0 + row) * KD + kt * 64 + c16s * 8;
      async_ld16(src, Bs + f16 * 16);
    }
    __syncthreads();

#pragma unroll
    for (int kk = 0; kk < 2; ++kk) {
      short8_t af[4], bfr[4];
#pragma unroll
      for (int mi = 0; mi < 4; ++mi) {
        int r = wm * 64 + mi * 16 + row16;
        int kb = kk * 128 + kgrp * 32;
        f32x4 lo = *(const f32x4*)(As + r * 256 + (kb ^ ((r & 7) << 4)));
        f32x4 hi = *(const f32x4*)(As + r * 256 + ((kb + 16) ^ ((r & 7) << 4)));
        union { short8_t v; unsigned short u[8]; } pk;
        pk.u[0] = f2bf(lo[0]); pk.u[1] = f2bf(lo[1]);
        pk.u[2] = f2bf(lo[2]); pk.u[3] = f2bf(lo[3]);
        pk.u[4] = f2bf(hi[0]); pk.u[5] = f2bf(hi[1]);
        pk.u[6] = f2bf(hi[2]); pk.u[7] = f2bf(hi[3]);
        af[mi] = pk.v;
      }
#pragma unroll
      for (int ni = 0; ni < 4; ++ni) {
        int r = wn * 64 + ni * 16 + row16;
        int kb = kk * 64 + kgrp * 16;
        bfr[ni] = *(const short8_t*)(Bs + r * 128 + (kb ^ ((r & 7) << 4)));
      }
#pragma unroll
      for (int mi = 0; mi < 4; ++mi)
#pragma unroll
        for (int ni = 0; ni < 4; ++ni)
          acc[mi][ni] = __builtin_amdgcn_mfma_f32_16x16x32_bf16(
              af[mi], bfr[ni], acc[mi][ni], 0, 0, 0);
    }
  }

#pragma unroll
  for (int mi = 0; mi < 4; ++mi) {
    size_t grow = m0 + (size_t)(wm * 64 + mi * 16 + kgrp * 4);
#pragma unroll
    for (int ni = 0; ni < 4; ++ni) {
      int col = n0 + wn * 64 + ni * 16 + row16;
      float bia = biasp[col];
      float* op = out + grow * DM + col;
#pragma unroll
      for (int r = 0; r < 4; ++r) op[(size_t)r * DM] = acc[mi][ni][r] + bia;
    }
  }
}

// ---------------- pass 2: grouped (d%7) RMS norm, in-place ----------------
__global__ __launch_bounds__(256) void norm_kernel(float* __restrict__ y,
                                                   const float* __restrict__ gamma) {
  const int tid = threadIdx.x, lane = tid & 63, wv = tid >> 6;
  const size_t row = (size_t)blockIdx.x * 4 + wv;   // one wave per row
  float4* rp = (float4*)(y + row * DM);
  const float4* gp = (const float4*)gamma;
  float4 v[4];
#pragma unroll
  for (int jj = 0; jj < 4; ++jj) v[jj] = rp[jj * 64 + lane];

  float ss[7] = {0.f, 0.f, 0.f, 0.f, 0.f, 0.f, 0.f};
#pragma unroll
  for (int jj = 0; jj < 4; ++jj) {
    const float vv[4] = {v[jj].x, v[jj].y, v[jj].z, v[jj].w};
#pragma unroll
    for (int i = 0; i < 4; ++i) {
      int d = (jj * 64 + lane) * 4 + i;
      int g = d % 7;
      float sq = vv[i] * vv[i];
#pragma unroll
      for (int t = 0; t < 7; ++t) ss[t] += (g == t) ? sq : 0.f;
    }
  }
#pragma unroll
  for (int t = 0; t < 7; ++t) {
#pragma unroll
    for (int off = 32; off >= 1; off >>= 1) ss[t] += __shfl_xor(ss[t], off, 64);
  }
  float inv[7];
#pragma unroll
  for (int t = 0; t < 7; ++t) {
    float cnt = (t < 2) ? 147.f : 146.f;   // D=1024: groups 0,1 have 147 dims
    inv[t] = rsqrtf(ss[t] / cnt + 1e-6f);
  }
#pragma unroll
  for (int jj = 0; jj < 4; ++jj) {
    float4 g4 = gp[jj * 64 + lane];
    const float vv[4] = {v[jj].x, v[jj].y, v[jj].z, v[jj].w};
    const float gg[4] = {g4.x, g4.y, g4.z, g4.w};
    float o[4];
#pragma unroll
    for (int i = 0; i < 4; ++i) {
      int d = (jj * 64 + lane) * 4 + i;
      int g = d % 7;
      float iv = inv[0];
#pragma unroll
      for (int t = 1; t < 7; ++t) iv = (g == t) ? inv[t] : iv;
      o[i] = vv[i] * iv * gg[i];
    }
    rp[jj * 64 + lane] = make_float4(o[0], o[1], o[2], o[3]);
  }
}

extern "C" void kernel_launch(void* const* d_in, const int* in_sizes, int n_in,
                              void* d_out, int out_size, void* d_ws, size_t ws_size,
                              hipStream_t stream) {
  const float* x     = (const float*)d_in[0];
  const float* W     = (const float*)d_in[1];
  const float* b     = (const float*)d_in[2];
  const float* theta = (const float*)d_in[3];
  const float* gamma = (const float*)d_in[4];
  float* out = (float*)d_out;
  (void)in_sizes; (void)n_in; (void)out_size;

  char* ws = (char*)d_ws;
  unsigned short* Wt = (unsigned short*)ws;                 // 6,291,456 B
  float* biasp = (float*)(ws + 6291456);                    // 4 KiB
  float* zp    = (float*)(ws + 6291456 + 4096);             // 4 KiB zeros
  unsigned short* xbp = (unsigned short*)(ws + 6299648);    // 67,158,016 B
  const size_t needA = 6299648 + (size_t)NB * 8194 * DM * 2;

  if (ws_size >= needA) {
    prep_all<<<dim3(769 + 4096), dim3(256), 0, stream>>>(
        x, W, b, theta, xbp, Wt, biasp, zp);
    gemm256<<<dim3(512), dim3(1024), 0, stream>>>(xbp, Wt, biasp, out);
  } else {
    prep_all<<<dim3(769), dim3(256), 0, stream>>>(
        x, W, b, theta, (unsigned short*)zp, Wt, biasp, zp);
    gemm_fb<<<dim3(2048), dim3(256), 0, stream>>>(x, Wt, biasp, zp, out);
  }
  norm_kernel<<<dim3(8192), dim3(256), 0, stream>>>(out, gamma);
}